// Round 12
// baseline (448.700 us; speedup 1.0000x reference)
//
#include <hip/hip_runtime.h>
#include <math.h>

#define BB 4096
#define TT 128
#define FF 256
#define VV 32
#define LN_EPS 1e-3f

typedef __attribute__((ext_vector_type(8))) short short8;
typedef __attribute__((ext_vector_type(4))) float f32x4;

template <int M> struct IC { static constexpr int value = M; };

__device__ __forceinline__ float sigm(float x) {
    return __builtin_amdgcn_rcpf(1.0f + __builtin_amdgcn_exp2f(-1.442695041f * x));
}
__device__ __forceinline__ float tanhfast(float x) {
    float e = __builtin_amdgcn_exp2f(2.885390082f * x);
    return 1.0f - 2.0f * __builtin_amdgcn_rcpf(e + 1.0f);
}
__device__ __forceinline__ unsigned short f2bf(float f) {
    union { float f; unsigned u; } v; v.f = f;
    unsigned r = v.u + 0x7FFFu + ((v.u >> 16) & 1u);   // RNE
    return (unsigned short)(r >> 16);
}
__device__ __forceinline__ float bf2f(unsigned short h) {
    union { unsigned u; float f; } v; v.u = ((unsigned)h) << 16; return v.f;
}

// =========== Kernel 1: LN + MLP via MFMA -> frag-ready seq (bf16 HI only, 4 dwords/row) ===========
__global__ __launch_bounds__(256, 3) void k_mlp2(
    const float* __restrict__ X, const int* __restrict__ Yp,
    const float* __restrict__ lng, const float* __restrict__ lnb,
    const float* __restrict__ W1, const float* __restrict__ b1,
    const float* __restrict__ bng, const float* __restrict__ bnb,
    const float* __restrict__ bnm, const float* __restrict__ bnv,
    const float* __restrict__ W2, const float* __restrict__ b2,
    const float* __restrict__ W3, const float* __restrict__ b3,
    unsigned int* __restrict__ sqpk, unsigned short* __restrict__ yv)
{
    __shared__ unsigned short w1fh[8192], w1fl[8192];
    __shared__ unsigned short w2fh[512], w2fl[512];
    __shared__ unsigned short w3fh[512], w3fl[512];
    __shared__ float bD1[32], bnSs[32], bnBs[32], b2s[16], b3s[8];
    __shared__ float e1s[4][16][33];
    __shared__ float e2s[4][16][17];

    const int tid = threadIdx.x;
    for (int e = tid; e < 8192; e += 256) {
        int j = e & 7, lane = (e >> 3) & 63, nt = (e >> 9) & 1, ks = e >> 10;
        int c = ks * 32 + (lane >> 4) * 8 + j;
        int n = nt * 16 + (lane & 15);
        float v = lng[c] * W1[c * 32 + n];
        unsigned short hi = f2bf(v);
        w1fh[e] = hi; w1fl[e] = f2bf(v - bf2f(hi));
    }
    for (int e = tid; e < 512; e += 256) {
        int j = e & 7, lane = e >> 3;
        int k = (lane >> 4) * 8 + j, n = lane & 15;
        float v2 = W2[k * 16 + n];
        unsigned short h2 = f2bf(v2);
        w2fh[e] = h2; w2fl[e] = f2bf(v2 - bf2f(h2));
        float v3 = (k < 16 && n < 8) ? W3[k * 8 + n] : 0.f;
        unsigned short h3 = f2bf(v3);
        w3fh[e] = h3; w3fl[e] = f2bf(v3 - bf2f(h3));
    }
    if (tid < 32) {
        float a = b1[tid];
        for (int c2 = 0; c2 < 256; ++c2) a += lnb[c2] * W1[c2 * 32 + tid];
        bD1[tid] = a;
        float sc = bng[tid] * rsqrtf(bnv[tid] + LN_EPS);
        bnSs[tid] = sc; bnBs[tid] = bnb[tid] - bnm[tid] * sc;
    } else if (tid < 48) b2s[tid - 32] = b2[tid - 32];
    else if (tid < 56) b3s[tid - 48] = b3[tid - 48];
    __syncthreads();

    const int wv = tid >> 6, l = tid & 63;
    const int r = l & 15, q = l >> 4;
    const int ntiles = (BB * TT) / 16;
    for (int tile = blockIdx.x * 4 + wv; tile < ntiles; tile += gridDim.x * 4) {
        const size_t rowbase = (size_t)tile * 16;
        const float* xrow = X + (rowbase + r) * FF + q * 8;
        float xd[64];
        #pragma unroll
        for (int ks = 0; ks < 8; ++ks) {
            float4 p0 = *(const float4*)(xrow + ks * 32);
            float4 p1 = *(const float4*)(xrow + ks * 32 + 4);
            xd[ks * 8 + 0] = p0.x; xd[ks * 8 + 1] = p0.y; xd[ks * 8 + 2] = p0.z; xd[ks * 8 + 3] = p0.w;
            xd[ks * 8 + 4] = p1.x; xd[ks * 8 + 5] = p1.y; xd[ks * 8 + 6] = p1.z; xd[ks * 8 + 7] = p1.w;
        }
        float s = 0.f, ss = 0.f;
        #pragma unroll
        for (int i = 0; i < 64; ++i) { s += xd[i]; ss += xd[i] * xd[i]; }
        s += __shfl_xor(s, 16);  s += __shfl_xor(s, 32);
        ss += __shfl_xor(ss, 16); ss += __shfl_xor(ss, 32);
        float mu = s * (1.0f / FF);
        float var = ss * (1.0f / FF) - mu * mu;
        float rs = rsqrtf(var + LN_EPS);

        f32x4 acc0 = {bD1[r], bD1[r], bD1[r], bD1[r]};
        f32x4 acc1 = {bD1[16 + r], bD1[16 + r], bD1[16 + r], bD1[16 + r]};
        #pragma unroll
        for (int ks = 0; ks < 8; ++ks) {
            short8 ah, al;
            #pragma unroll
            for (int j = 0; j < 8; ++j) {
                float xn = (xd[ks * 8 + j] - mu) * rs;
                unsigned short hi = f2bf(xn);
                ah[j] = (short)hi; al[j] = (short)f2bf(xn - bf2f(hi));
            }
            short8 bh0 = *(const short8*)&w1fh[((ks * 2 + 0) * 64 + l) * 8];
            short8 bl0 = *(const short8*)&w1fl[((ks * 2 + 0) * 64 + l) * 8];
            short8 bh1 = *(const short8*)&w1fh[((ks * 2 + 1) * 64 + l) * 8];
            short8 bl1 = *(const short8*)&w1fl[((ks * 2 + 1) * 64 + l) * 8];
            acc0 = __builtin_amdgcn_mfma_f32_16x16x32_bf16(ah, bh0, acc0, 0, 0, 0);
            acc0 = __builtin_amdgcn_mfma_f32_16x16x32_bf16(al, bh0, acc0, 0, 0, 0);
            acc0 = __builtin_amdgcn_mfma_f32_16x16x32_bf16(ah, bl0, acc0, 0, 0, 0);
            acc1 = __builtin_amdgcn_mfma_f32_16x16x32_bf16(ah, bh1, acc1, 0, 0, 0);
            acc1 = __builtin_amdgcn_mfma_f32_16x16x32_bf16(al, bh1, acc1, 0, 0, 0);
            acc1 = __builtin_amdgcn_mfma_f32_16x16x32_bf16(ah, bl1, acc1, 0, 0, 0);
        }
        #pragma unroll
        for (int i = 0; i < 4; ++i) {
            int row = q * 4 + i;
            float z0 = fmaxf(acc0[i], 0.f) * bnSs[r] + bnBs[r];
            float z1 = fmaxf(acc1[i], 0.f) * bnSs[16 + r] + bnBs[16 + r];
            e1s[wv][row][r] = z0;
            e1s[wv][row][16 + r] = z1;
        }
        __builtin_amdgcn_wave_barrier();

        short8 a2h, a2l;
        #pragma unroll
        for (int j = 0; j < 8; ++j) {
            float v = e1s[wv][r][q * 8 + j];
            unsigned short hi = f2bf(v);
            a2h[j] = (short)hi; a2l[j] = (short)f2bf(v - bf2f(hi));
        }
        f32x4 acc2 = {b2s[r], b2s[r], b2s[r], b2s[r]};
        {
            short8 bh = *(const short8*)&w2fh[l * 8];
            short8 bl = *(const short8*)&w2fl[l * 8];
            acc2 = __builtin_amdgcn_mfma_f32_16x16x32_bf16(a2h, bh, acc2, 0, 0, 0);
            acc2 = __builtin_amdgcn_mfma_f32_16x16x32_bf16(a2l, bh, acc2, 0, 0, 0);
            acc2 = __builtin_amdgcn_mfma_f32_16x16x32_bf16(a2h, bl, acc2, 0, 0, 0);
        }
        #pragma unroll
        for (int i = 0; i < 4; ++i) e2s[wv][q * 4 + i][r] = fmaxf(acc2[i], 0.f);
        __builtin_amdgcn_wave_barrier();

        short8 a3h = (short8){0,0,0,0,0,0,0,0}, a3l = (short8){0,0,0,0,0,0,0,0};
        if (q < 2) {
            #pragma unroll
            for (int j = 0; j < 8; ++j) {
                float v = e2s[wv][r][q * 8 + j];
                unsigned short hi = f2bf(v);
                a3h[j] = (short)hi; a3l[j] = (short)f2bf(v - bf2f(hi));
            }
        }
        float b3v = (r < 8) ? b3s[r] : 0.f;
        f32x4 acc3 = {b3v, b3v, b3v, b3v};
        {
            short8 bh = *(const short8*)&w3fh[l * 8];
            short8 bl = *(const short8*)&w3fl[l * 8];
            acc3 = __builtin_amdgcn_mfma_f32_16x16x32_bf16(a3h, bh, acc3, 0, 0, 0);
            acc3 = __builtin_amdgcn_mfma_f32_16x16x32_bf16(a3l, bh, acc3, 0, 0, 0);
            acc3 = __builtin_amdgcn_mfma_f32_16x16x32_bf16(a3h, bl, acc3, 0, 0, 0);
        }
        // hi-only frag-ready store: even r packs (hi_{r+1}<<16)|hi_r at dword r/2
        if (r < 8) {
            #pragma unroll
            for (int i = 0; i < 4; ++i) {
                size_t grow = rowbase + q * 4 + i;
                float e3 = fmaxf(acc3[i], 0.f);
                unsigned int wself = (unsigned)f2bf(e3);
                unsigned int wnbr = __shfl_xor(wself, 1);
                if ((r & 1) == 0) sqpk[grow * 4 + (r >> 1)] = (wnbr << 16) | wself;
            }
        } else if (r == 8) {
            #pragma unroll
            for (int i = 0; i < 4; ++i) {
                size_t grow = rowbase + q * 4 + i;
                yv[grow] = f2bf((float)Yp[grow]);
            }
        }
        __builtin_amdgcn_wave_barrier();
    }
}

// ===== Kernel 2a: SINGLE-direction batch-8 BiLSTM block (256 thr, 4 waves) =====
// 2 blocks/CU co-resident -> each SIMD's 2 waves are from INDEPENDENT barrier groups,
// so one block's barrier stall is hidden by the other block's issue. Row mapping
// rho(s)=(s>>1)*4+(s&1) proven in r8. Pure bf16-hi (r11-proven numerics).
#define R2_SEQ 0u         // u32 [TT][36] (8 smp x 4 dw + pad) = 18432
#define R2_YV  18432u     // u16 [TT][8]                       = 2048
#define R2_HP  20480u     // u32 [2][16][36]                   = 4608
#define R2_SZ  25088u

__global__ __launch_bounds__(256, 2) void k_rnn2(
    const unsigned int* __restrict__ g_sqpk, const unsigned short* __restrict__ g_yv,
    const float* __restrict__ fk, const float* __restrict__ fr, const float* __restrict__ fb,
    const float* __restrict__ bk, const float* __restrict__ br, const float* __restrict__ bbv,
    unsigned int* __restrict__ enc,                       // chunk-local [csmp][T][64] dwords
    float* __restrict__ hfin, float* __restrict__ cfin,   // absolute [B][128]
    int s0)
{
    __shared__ __align__(16) unsigned char arena[R2_SZ];
    unsigned int*   seqU   = (unsigned int*)(arena + R2_SEQ);
    unsigned short* yvS    = (unsigned short*)(arena + R2_YV);
    unsigned int*   hpackU = (unsigned int*)(arena + R2_HP);

    const int tid = threadIdx.x;
    const int grp = blockIdx.x >> 1;          // sample group (8 samples)
    const int d = blockIdx.x & 1;             // direction
    const int sbase = s0 + grp * 8;
    const int w = tid >> 6, l = tid & 63;
    const int r = l & 15, q = l >> 4;
    const int u = (w << 4) + r;
    const int rb = r & 3;
    const int live = (rb < 2);
    const int sloc = (r >> 2) * 2 + rb;       // sample slot carried by A-row r

    // stage hi-only seq (8 samples) + y
    for (int i = tid; i < 8 * TT * 4; i += 256) {
        int smp = i >> 9, rem = i & 511;
        int t = rem >> 2, j = rem & 3;
        seqU[t * 36 + smp * 4 + j] = g_sqpk[(size_t)(sbase + smp) * (TT * 4) + rem];
    }
    for (int i = tid; i < 8 * TT; i += 256) {
        int smp = i >> 7, t = i & 127;
        yvS[t * 8 + smp] = g_yv[(size_t)(sbase + smp) * TT + t];
    }

    const float* Wr = d ? br : fr;
    const float* Wk = d ? bk : fk;
    const float* Bz = d ? bbv : fb;
    short8 Bh[3][4];
    float bz[4];
    #pragma unroll
    for (int g = 0; g < 4; ++g) {
        int col = (g << 6) + u;
        bz[g] = Bz[col];
        #pragma unroll
        for (int kt = 0; kt < 3; ++kt) {
            #pragma unroll
            for (int j = 0; j < 8; ++j) {
                int kg = kt * 32 + q * 8 + j;
                float v = (kg < 64) ? Wr[kg * 256 + col]
                        : (kg < 73) ? Wk[(kg - 64) * 256 + col] : 0.f;
                Bh[kt][g][j] = (short)f2bf(v);
            }
        }
    }

    const unsigned int* hrd0 = hpackU + r * 36 + q * 4;
    const unsigned int* hrd1 = hrd0 + 576;                 // + 16*36
    const int wofs = w * 8 + (r >> 1);                     // hi-pair dword (even r writes)
    const int elb = ((grp * 8 + q * 2) * TT) * 64 + d * 32 + (u >> 1);

    for (int i = tid; i < 1152; i += 256) hpackU[i] = 0u;
    float c4[2] = {0.f, 0.f};
    __syncthreads();

    auto ldA2 = [&](int ts_) -> short8 {
        short8 v = (short8){0,0,0,0,0,0,0,0};
        if (q == 0) {
            if (live) v = *(const short8*)(seqU + ts_ * 36 + sloc * 4);
        } else if (q == 1) {
            if (live) v[0] = (short)yvS[ts_ * 8 + sloc];
        }
        return v;
    };
    short8 A2h = ldA2(d ? (TT - 1) : 0);

    for (int t = 0; t < TT; ++t) {
        const int ts = d ? (TT - 1 - t) : t;
        const int buf = t & 1;
        const unsigned int* hp = buf ? hrd1 : hrd0;
        short8 A0h = *(const short8*)(hp);
        short8 A1h = *(const short8*)(hp + 16);
        short8 A2c = A2h;

        f32x4 z[4];
        #pragma unroll
        for (int g = 0; g < 4; ++g) {
            f32x4 acc = {bz[g], bz[g], bz[g], bz[g]};
            acc = __builtin_amdgcn_mfma_f32_16x16x32_bf16(A0h, Bh[0][g], acc, 0, 0, 0);
            acc = __builtin_amdgcn_mfma_f32_16x16x32_bf16(A1h, Bh[1][g], acc, 0, 0, 0);
            acc = __builtin_amdgcn_mfma_f32_16x16x32_bf16(A2c, Bh[2][g], acc, 0, 0, 0);
            z[g] = acc;
        }

        if (t < TT - 1) A2h = ldA2(d ? (TT - 2 - t) : (t + 1));

        const int nb = (buf ^ 1) * 576;
        #pragma unroll
        for (int i = 0; i < 2; ++i) {          // C/D rows q*4+i -> samples q*2+i
            float zi = z[0][i], zf = z[1][i], zg = z[2][i], zo = z[3][i];
            float cc = sigm(zf) * c4[i] + sigm(zi) * tanhfast(zg);
            float hh = sigm(zo) * tanhfast(cc);
            c4[i] = cc;
            unsigned int wself = (unsigned)f2bf(hh);
            unsigned int wnbr = __shfl_xor(wself, 1);
            if ((r & 1) == 0) {
                unsigned int outw = (wnbr << 16) | wself;
                hpackU[nb + (q * 4 + i) * 36 + wofs] = outw;
                enc[elb + i * (TT * 64) + ts * 64] = outw;
            }
            if (t == TT - 1) {
                hfin[(size_t)(sbase + q * 2 + i) * 128 + (d << 6) + u] = hh;
                cfin[(size_t)(sbase + q * 2 + i) * 128 + (d << 6) + u] = cc;
            }
        }
        // LDS-only barrier (4 waves): global stores stay in flight.
        asm volatile("s_waitcnt lgkmcnt(0)\n\ts_barrier" ::: "memory");
    }
}

// ------- Kernel 2b: per-sample attention + decoder + output softmax (proven) -------
__global__ __launch_bounds__(256, 4) void k_att(
    const unsigned short* __restrict__ enc,
    const float* __restrict__ hfin, const float* __restrict__ cfin,
    const float* __restrict__ Wsh, const float* __restrict__ bsh,
    const float* __restrict__ Wsc, const float* __restrict__ bsc,
    const float* __restrict__ Wq,  const float* __restrict__ bq,
    const float* __restrict__ dk,  const float* __restrict__ dr, const float* __restrict__ dbv,
    const float* __restrict__ Wo,  const float* __restrict__ bo,
    float* __restrict__ out, int s0)
{
    __shared__ unsigned short el[TT][136];
    __shared__ float st[128], ct[128], shS[64], scS[64], qS[128], pS[128], attS[128], zdS[256], hdS[64], red[8];

    int tid = threadIdx.x;
    int bloc = blockIdx.x;
    int s = s0 + bloc;

    for (int i = tid; i < TT * 16; i += 256) {
        int t = i >> 4, c = i & 15;
        *(short8*)&el[t][c * 8] = *(const short8*)&enc[(size_t)bloc * TT * 128 + t * 128 + c * 8];
    }
    if (tid < 128) { st[tid] = hfin[(size_t)s * 128 + tid]; ct[tid] = cfin[(size_t)s * 128 + tid]; }
    __syncthreads();

    if (tid < 128) {
        int uu = tid & 63;
        const float* Wm = (tid < 64) ? Wsh : Wsc;
        const float* sv = (tid < 64) ? st : ct;
        float a = (tid < 64) ? bsh[uu] : bsc[uu];
        #pragma unroll 4
        for (int j = 0; j < 128; ++j) a += sv[j] * Wm[j * 64 + uu];
        if (tid < 64) shS[uu] = a; else scS[uu] = a;
    }
    __syncthreads();
    if (tid < 128) {
        float a = bq[tid];
        #pragma unroll 4
        for (int uu = 0; uu < 64; ++uu) a += shS[uu] * Wq[uu * 128 + tid];
        qS[tid] = a;
    }
    __syncthreads();
    float sc_val = 0.f;
    int wvv = tid >> 6, lnn = tid & 63;
    if (tid < 128) {
        float a = 0.f;
        #pragma unroll 2
        for (int c = 0; c < 16; ++c) {
            short8 e8 = *(const short8*)&el[tid][c * 8];
            #pragma unroll
            for (int j2 = 0; j2 < 8; ++j2) a += qS[c * 8 + j2] * bf2f((unsigned short)e8[j2]);
        }
        sc_val = a;
        float m = a;
        #pragma unroll
        for (int mk = 1; mk < 64; mk <<= 1) m = fmaxf(m, __shfl_xor(m, mk));
        if (lnn == 0) red[wvv] = m;
    }
    __syncthreads();
    float gmax = fmaxf(red[0], red[1]);
    if (tid < 128) {
        float ev = expf(sc_val - gmax);
        pS[tid] = ev;
        float s2 = ev;
        #pragma unroll
        for (int mk = 1; mk < 64; mk <<= 1) s2 += __shfl_xor(s2, mk);
        if (lnn == 0) red[4 + wvv] = s2;
    }
    __syncthreads();
    float denom = red[4] + red[5];
    if (tid < 128) {
        float a = 0.f;
        #pragma unroll 4
        for (int t2 = 0; t2 < TT; ++t2) a += pS[t2] * bf2f(el[t2][tid]);
        attS[tid] = a / denom;
    }
    __syncthreads();
    if (tid < 256) {
        float a = dbv[tid];
        #pragma unroll 4
        for (int j = 0; j < 128; ++j) a += attS[j] * dk[j * 256 + tid];
        #pragma unroll 4
        for (int j = 0; j < 64; ++j)  a += shS[j] * dr[j * 256 + tid];
        zdS[tid] = a;
    }
    __syncthreads();
    if (tid < 64) {
        float zi = zdS[tid], zf = zdS[64 + tid], zg = zdS[128 + tid], zo = zdS[192 + tid];
        float cc = sigm(zf) * scS[tid] + sigm(zi) * tanhfast(zg);
        hdS[tid] = sigm(zo) * tanhfast(cc);
    }
    __syncthreads();
    if (tid < 32) {
        float a = bo[tid];
        #pragma unroll
        for (int uu = 0; uu < 64; ++uu) a += hdS[uu] * Wo[uu * 32 + tid];
        float m = a;
        #pragma unroll
        for (int mk = 1; mk < 32; mk <<= 1) m = fmaxf(m, __shfl_xor(m, mk));
        float e = expf(a - m);
        float s2 = e;
        #pragma unroll
        for (int mk = 1; mk < 32; mk <<= 1) s2 += __shfl_xor(s2, mk);
        out[(size_t)s * VV + tid] = e / s2;
    }
}

// ====== Kernel 2-fallback: fused 3-pass (r6-proven, hi-only seq; used only for tiny ws) ======
#define A_SEQ   0u
#define A_YV    34816u
#define A_HP    38912u
#define A_SGRID 56320u
#define A_SH    72704u
#define A_SC    76800u
#define A_Q     80896u
#define A_ATT   89088u
#define A_L     97280u
#define A_SZ    97344u

__global__ __launch_bounds__(512, 1) void k_rnn(
    const unsigned int* __restrict__ g_sqpk, const unsigned short* __restrict__ g_yv,
    const float* __restrict__ fk, const float* __restrict__ fr, const float* __restrict__ fb,
    const float* __restrict__ bk, const float* __restrict__ br, const float* __restrict__ bbv,
    const float* __restrict__ Wsh, const float* __restrict__ bsh,
    const float* __restrict__ Wsc, const float* __restrict__ bsc,
    const float* __restrict__ Wq,  const float* __restrict__ bq,
    const float* __restrict__ dk,  const float* __restrict__ dr, const float* __restrict__ db,
    const float* __restrict__ Wo,  const float* __restrict__ bo,
    float* __restrict__ out)
{
    __shared__ __align__(16) unsigned char arena[A_SZ];
    unsigned int*   seqU   = (unsigned int*)(arena + A_SEQ);
    unsigned short* yvS    = (unsigned short*)(arena + A_YV);
    unsigned int*   hpackU = (unsigned int*)(arena + A_HP);
    float* sgridF = (float*)(arena + A_SGRID);
    float* hfinL  = (float*)(arena + A_SGRID);
    float* cfinL  = hfinL + 2048;
    float* zdS    = (float*)(arena + A_SGRID);
    float* shS    = (float*)(arena + A_SH);
    float* scS    = (float*)(arena + A_SC);
    float* qS     = (float*)(arena + A_Q);
    float* pT     = (float*)(arena + A_Q);
    float* attS   = (float*)(arena + A_ATT);
    float* hdS    = (float*)(arena + A_ATT);
    float* lS     = (float*)(arena + A_L);

    const int tid = threadIdx.x;
    const int sbase = blockIdx.x * 16;
    const int wv = tid >> 6, l = tid & 63;
    const int d = wv >> 2, w = wv & 3;
    const int r = l & 15, q = l >> 4;
    const int u = (w << 4) + r;

    for (int i = tid; i < 16 * TT * 4; i += 512) {
        int smp = i >> 9, rem = i & 511;
        int t = rem >> 2, j = rem & 3;
        seqU[t * 68 + smp * 4 + j] = g_sqpk[(size_t)(sbase + smp) * (TT * 4) + rem];
    }
    for (int i = tid; i < 16 * TT; i += 512) {
        int smp = i >> 7, t = i & 127;
        yvS[t * 16 + smp] = g_yv[(size_t)(sbase + smp) * TT + t];
    }

    const float* Wr = d ? br : fr;
    const float* Wk = d ? bk : fk;
    const float* Bz = d ? bbv : fb;
    short8 Bh[3][4], Bl[3][4];
    float bz[4];
    #pragma unroll
    for (int g = 0; g < 4; ++g) {
        int col = (g << 6) + u;
        bz[g] = Bz[col];
        #pragma unroll
        for (int kt = 0; kt < 3; ++kt) {
            #pragma unroll
            for (int j = 0; j < 8; ++j) {
                int kg = kt * 32 + q * 8 + j;
                float v = (kg < 64) ? Wr[kg * 256 + col]
                        : (kg < 73) ? Wk[(kg - 64) * 256 + col] : 0.f;
                unsigned short hi = f2bf(v);
                Bh[kt][g][j] = (short)hi;
                Bl[kt][g][j] = (short)f2bf(v - bf2f(hi));
            }
        }
    }
    short8 Bq0h = (short8){0,0,0,0,0,0,0,0}, Bq1h = (short8){0,0,0,0,0,0,0,0};

    const unsigned int* hrd0 = hpackU + (d * 16 + r) * 68 + q * 4;
    const unsigned int* hrd1 = hrd0 + 2176;
    const int wofs = w * 8 + (r >> 1) + ((r & 1) ? 32 : 0);
    __syncthreads();

    auto run_phase = [&](auto mode_c) {
        constexpr int mode = decltype(mode_c)::value;
        for (int i = tid; i < 4352; i += 512) hpackU[i] = 0u;
        float c4[4] = {0.f, 0.f, 0.f, 0.f};
        float aacc[4] = {0.f, 0.f, 0.f, 0.f};
        __syncthreads();
        for (int t = 0; t < TT; ++t) {
            const int ts = d ? (TT - 1 - t) : t;
            const int buf = t & 1;
            const unsigned int* hp = buf ? hrd1 : hrd0;
            short8 A0h = *(const short8*)(hp);
            short8 A1h = *(const short8*)(hp + 16);
            short8 A0l = *(const short8*)(hp + 32);
            short8 A1l = *(const short8*)(hp + 48);
            short8 A2h = (short8){0,0,0,0,0,0,0,0};
            if (q == 0) {
                A2h = *(const short8*)(seqU + ts * 68 + r * 4);
            } else if (q == 1) {
                A2h[0] = (short)yvS[ts * 16 + r];
            }
            if constexpr (mode == 1) {
                if (w == 0 && t > 0) {
                    f32x4 sa = {0.f, 0.f, 0.f, 0.f};
                    sa = __builtin_amdgcn_mfma_f32_16x16x32_bf16(A0h, Bq0h, sa, 0, 0, 0);
                    sa = __builtin_amdgcn_mfma_f32_16x16x32_bf16(A1h, Bq1h, sa, 0, 0, 0);
                    if (q == (r >> 2)) {
                        int tp = d ? (TT - t) : (t - 1);
                        sgridF[(d * 16 + r) * 128 + tp] = sa[r & 3];
                    }
                }
            }
            f32x4 z[4];
            #pragma unroll
            for (int g = 0; g < 4; ++g) {
                f32x4 acc = {bz[g], bz[g], bz[g], bz[g]};
                acc = __builtin_amdgcn_mfma_f32_16x16x32_bf16(A0h, Bh[0][g], acc, 0, 0, 0);
                acc = __builtin_amdgcn_mfma_f32_16x16x32_bf16(A0l, Bh[0][g], acc, 0, 0, 0);
                acc = __builtin_amdgcn_mfma_f32_16x16x32_bf16(A0h, Bl[0][g], acc, 0, 0, 0);
                acc = __builtin_amdgcn_mfma_f32_16x16x32_bf16(A1h, Bh[1][g], acc, 0, 0, 0);
                acc = __builtin_amdgcn_mfma_f32_16x16x32_bf16(A1l, Bh[1][g], acc, 0, 0, 0);
                acc = __builtin_amdgcn_mfma_f32_16x16x32_bf16(A1h, Bl[1][g], acc, 0, 0, 0);
                acc = __builtin_amdgcn_mfma_f32_16x16x32_bf16(A2h, Bh[2][g], acc, 0, 0, 0);
                acc = __builtin_amdgcn_mfma_f32_16x16x32_bf16(A2h, Bl[2][g], acc, 0, 0, 0);
                z[g] = acc;
            }
            const int nbase = ((buf ^ 1) * 2 + d) * 16;
            #pragma unroll
            for (int i = 0; i < 4; ++i) {
                float zi = z[0][i], zf = z[1][i], zg = z[2][i], zo = z[3][i];
                float cc = sigm(zf) * c4[i] + sigm(zi) * tanhfast(zg);
                float hh = sigm(zo) * tanhfast(cc);
                c4[i] = cc;
                int smp = (q << 2) + i;
                unsigned short bfh = f2bf(hh);
                unsigned short bfe = f2bf(hh - bf2f(bfh));
                unsigned int wself = ((unsigned)bfh << 16) | (unsigned)bfe;
                unsigned int wnbr = __shfl_xor(wself, 1);
                unsigned int outw = (r & 1) ? ((wself << 16) | (wnbr & 0xFFFFu))
                                            : ((wnbr & 0xFFFF0000u) | (wself >> 16));
                hpackU[(nbase + smp) * 68 + wofs] = outw;
                if constexpr (mode == 2) aacc[i] += pT[ts * 16 + smp] * hh;
                if constexpr (mode == 0) {
                    if (t == TT - 1) {
                        hfinL[smp * 128 + (d << 6) + u] = hh;
                        cfinL[smp * 128 + (d << 6) + u] = cc;
                    }
                }
            }
            __syncthreads();
        }
        if constexpr (mode == 1) {
            if (w == 0) {
                short8 A0h = *(const short8*)(hrd0);
                short8 A1h = *(const short8*)(hrd0 + 16);
                f32x4 sa = {0.f, 0.f, 0.f, 0.f};
                sa = __builtin_amdgcn_mfma_f32_16x16x32_bf16(A0h, Bq0h, sa, 0, 0, 0);
                sa = __builtin_amdgcn_mfma_f32_16x16x32_bf16(A1h, Bq1h, sa, 0, 0, 0);
                if (q == (r >> 2)) {
                    int tp = d ? 0 : (TT - 1);
                    sgridF[(d * 16 + r) * 128 + tp] = sa[r & 3];
                }
            }
            __syncthreads();
        }
        if constexpr (mode == 2) {
            #pragma unroll
            for (int i = 0; i < 4; ++i) {
                int smp = (q << 2) + i;
                attS[smp * 128 + (d << 6) + u] = aacc[i] / lS[smp];
            }
            __syncthreads();
        }
    };

    run_phase(IC<0>{});
    for (int o = tid; o < 2048; o += 512) {
        int kind = o >> 10, smp = (o >> 6) & 15, uu = o & 63;
        const float* src = kind ? (cfinL + smp * 128) : (hfinL + smp * 128);
        const float* Wm = kind ? Wsc : Wsh;
        float a = kind ? bsc[uu] : bsh[uu];
        #pragma unroll 4
        for (int j = 0; j < 128; ++j) a += src[j] * Wm[j * 64 + uu];
        (kind ? scS : shS)[smp * 64 + uu] = a;
    }
    __syncthreads();
    for (int o = tid; o < 2048; o += 512) {
        int smp = o >> 7, dd = o & 127;
        float a = bq[dd];
        #pragma unroll 4
        for (int j = 0; j < 64; ++j) a += shS[smp * 64 + j] * Wq[j * 128 + dd];
        qS[smp * 128 + dd] = a;
    }
    __syncthreads();
    if (w == 0) {
        #pragma unroll
        for (int j = 0; j < 8; ++j) {
            Bq0h[j] = (short)f2bf(qS[r * 128 + (d << 6) + q * 8 + j]);
            Bq1h[j] = (short)f2bf(qS[r * 128 + (d << 6) + 32 + q * 8 + j]);
        }
    }
    __syncthreads();

    run_phase(IC<1>{});
    {
        int smp = tid >> 5, sl = tid & 31;
        float sv[4];
        #pragma unroll
        for (int p = 0; p < 4; ++p) {
            int t = sl + 32 * p;
            sv[p] = sgridF[smp * 128 + t] + sgridF[(16 + smp) * 128 + t];
        }
        float m = fmaxf(fmaxf(sv[0], sv[1]), fmaxf(sv[2], sv[3]));
        #pragma unroll
        for (int mk = 1; mk < 32; mk <<= 1) m = fmaxf(m, __shfl_xor(m, mk));
        float lsum = 0.f;
        #pragma unroll
        for (int p = 0; p < 4; ++p) lsum += __expf(sv[p] - m);
        #pragma unroll
        for (int mk = 1; mk < 32; mk <<= 1) lsum += __shfl_xor(lsum, mk);
        __syncthreads();
        #pragma unroll
        for (int p = 0; p < 4; ++p) pT[(sl + 32 * p) * 16 + smp] = __expf(sv[p] - m);
        if (sl == 0) lS[smp] = lsum;
    }
    __syncthreads();

    run_phase(IC<2>{});

    for (int o = tid; o < 4096; o += 512) {
        int smp = o >> 8, col = o & 255;
        float a = db[col];
        #pragma unroll 4
        for (int j = 0; j < 128; ++j) a += attS[smp * 128 + j] * dk[j * 256 + col];
        #pragma unroll 4
        for (int j = 0; j < 64; ++j)  a += shS[smp * 64 + j] * dr[j * 256 + col];
        zdS[smp * 256 + col] = a;
    }
    __syncthreads();
    for (int o = tid; o < 1024; o += 512) {
        int smp = o >> 6, uu = o & 63;
        float zi = zdS[smp * 256 + uu], zf = zdS[smp * 256 + 64 + uu];
        float zg = zdS[smp * 256 + 128 + uu], zo = zdS[smp * 256 + 192 + uu];
        float cc = sigm(zf) * scS[smp * 64 + uu] + sigm(zi) * tanhfast(zg);
        hdS[smp * 64 + uu] = sigm(zo) * tanhfast(cc);
    }
    __syncthreads();
    {
        int smp = tid >> 5, v = tid & 31;
        float a = bo[v];
        #pragma unroll 4
        for (int j = 0; j < 64; ++j) a += hdS[smp * 64 + j] * Wo[j * 32 + v];
        float m = a;
        #pragma unroll
        for (int mk = 1; mk < 32; mk <<= 1) m = fmaxf(m, __shfl_xor(m, mk));
        float e = __expf(a - m);
        float s2 = e;
        #pragma unroll
        for (int mk = 1; mk < 32; mk <<= 1) s2 += __shfl_xor(s2, mk);
        out[(size_t)(sbase + smp) * VV + v] = e / s2;
    }
}

extern "C" void kernel_launch(void* const* d_in, const int* in_sizes, int n_in,
                              void* d_out, int out_size, void* d_ws, size_t ws_size,
                              hipStream_t stream) {
    const float* X   = (const float*)d_in[0];
    const int*   Yp  = (const int*)d_in[1];
    const float* lng = (const float*)d_in[2];
    const float* lnb = (const float*)d_in[3];
    const float* W1  = (const float*)d_in[4];
    const float* b1  = (const float*)d_in[5];
    const float* bng = (const float*)d_in[6];
    const float* bnb = (const float*)d_in[7];
    const float* bnm = (const float*)d_in[8];
    const float* bnv = (const float*)d_in[9];
    const float* W2  = (const float*)d_in[10];
    const float* b2  = (const float*)d_in[11];
    const float* W3  = (const float*)d_in[12];
    const float* b3  = (const float*)d_in[13];
    const float* fk  = (const float*)d_in[14];
    const float* fr  = (const float*)d_in[15];
    const float* fb  = (const float*)d_in[16];
    const float* bk  = (const float*)d_in[17];
    const float* br  = (const float*)d_in[18];
    const float* bbv = (const float*)d_in[19];
    const float* Wsh = (const float*)d_in[20];
    const float* bsh = (const float*)d_in[21];
    const float* Wsc = (const float*)d_in[22];
    const float* bsc = (const float*)d_in[23];
    const float* Wq  = (const float*)d_in[24];
    const float* bq  = (const float*)d_in[25];
    const float* dk  = (const float*)d_in[26];
    const float* dr  = (const float*)d_in[27];
    const float* db  = (const float*)d_in[28];
    const float* Wo  = (const float*)d_in[29];
    const float* bo  = (const float*)d_in[30];

    // ws: sqpk u32[B*T*4] (8MB) | yv u16[B*T] (1MB) | hfin/cfin f32[B*128] (4MB) | enc u16[cs*T*128]
    unsigned int*   sqpk = (unsigned int*)d_ws;
    unsigned short* yv   = (unsigned short*)(sqpk + (size_t)BB * TT * 4);
    float*          hfin = (float*)(yv + (size_t)BB * TT);
    float*          cfin = hfin + (size_t)BB * 128;
    unsigned int*   encp = (unsigned int*)(cfin + (size_t)BB * 128);
    const size_t baseB = (size_t)((char*)encp - (char*)d_ws);
    const size_t encFull = (size_t)BB * TT * 128 * 2;

    int nch = 0;
    if      (ws_size >= baseB + encFull)     nch = 1;
    else if (ws_size >= baseB + encFull / 2) nch = 2;
    else if (ws_size >= baseB + encFull / 4) nch = 4;
    else if (ws_size >= baseB + encFull / 8) nch = 8;

    k_mlp2<<<768, 256, 0, stream>>>(X, Yp, lng, lnb, W1, b1, bng, bnb, bnm, bnv,
                                    W2, b2, W3, b3, sqpk, yv);
    if (nch) {
        const int cs = BB / nch;
        for (int c = 0; c < nch; ++c) {
            int s0 = c * cs;
            k_rnn2<<<cs / 4, 256, 0, stream>>>(sqpk, yv, fk, fr, fb, bk, br, bbv,
                                               encp, hfin, cfin, s0);
            k_att<<<cs, 256, 0, stream>>>((const unsigned short*)encp, hfin, cfin,
                                          Wsh, bsh, Wsc, bsc, Wq, bq,
                                          dk, dr, db, Wo, bo, (float*)d_out, s0);
        }
    } else {
        k_rnn<<<BB / 16, 512, 0, stream>>>(sqpk, yv, fk, fr, fb, bk, br, bbv,
                                           Wsh, bsh, Wsc, bsc, Wq, bq, dk, dr, db, Wo, bo,
                                           (float*)d_out);
    }
}

// Round 13
// 408.776 us; speedup vs baseline: 1.0977x; 1.0977x over previous
//
#include <hip/hip_runtime.h>
#include <math.h>

#define BB 4096
#define TT 128
#define FF 256
#define VV 32
#define LN_EPS 1e-3f

typedef __attribute__((ext_vector_type(8))) short short8;
typedef __attribute__((ext_vector_type(4))) float f32x4;

template <int M> struct IC { static constexpr int value = M; };

__device__ __forceinline__ float sigm(float x) {
    return __builtin_amdgcn_rcpf(1.0f + __builtin_amdgcn_exp2f(-1.442695041f * x));
}
__device__ __forceinline__ float tanhfast(float x) {
    float e = __builtin_amdgcn_exp2f(2.885390082f * x);
    return 1.0f - 2.0f * __builtin_amdgcn_rcpf(e + 1.0f);
}
__device__ __forceinline__ unsigned short f2bf(float f) {
    union { float f; unsigned u; } v; v.f = f;
    unsigned r = v.u + 0x7FFFu + ((v.u >> 16) & 1u);   // RNE
    return (unsigned short)(r >> 16);
}
__device__ __forceinline__ float bf2f(unsigned short h) {
    union { unsigned u; float f; } v; v.u = ((unsigned)h) << 16; return v.f;
}

// =========== Kernel 1: LN + MLP via MFMA -> frag-ready seq (bf16 HI only, 4 dwords/row) ===========
__global__ __launch_bounds__(256, 3) void k_mlp2(
    const float* __restrict__ X, const int* __restrict__ Yp,
    const float* __restrict__ lng, const float* __restrict__ lnb,
    const float* __restrict__ W1, const float* __restrict__ b1,
    const float* __restrict__ bng, const float* __restrict__ bnb,
    const float* __restrict__ bnm, const float* __restrict__ bnv,
    const float* __restrict__ W2, const float* __restrict__ b2,
    const float* __restrict__ W3, const float* __restrict__ b3,
    unsigned int* __restrict__ sqpk, unsigned short* __restrict__ yv)
{
    __shared__ unsigned short w1fh[8192], w1fl[8192];
    __shared__ unsigned short w2fh[512], w2fl[512];
    __shared__ unsigned short w3fh[512], w3fl[512];
    __shared__ float bD1[32], bnSs[32], bnBs[32], b2s[16], b3s[8];
    __shared__ float e1s[4][16][33];
    __shared__ float e2s[4][16][17];

    const int tid = threadIdx.x;
    for (int e = tid; e < 8192; e += 256) {
        int j = e & 7, lane = (e >> 3) & 63, nt = (e >> 9) & 1, ks = e >> 10;
        int c = ks * 32 + (lane >> 4) * 8 + j;
        int n = nt * 16 + (lane & 15);
        float v = lng[c] * W1[c * 32 + n];
        unsigned short hi = f2bf(v);
        w1fh[e] = hi; w1fl[e] = f2bf(v - bf2f(hi));
    }
    for (int e = tid; e < 512; e += 256) {
        int j = e & 7, lane = e >> 3;
        int k = (lane >> 4) * 8 + j, n = lane & 15;
        float v2 = W2[k * 16 + n];
        unsigned short h2 = f2bf(v2);
        w2fh[e] = h2; w2fl[e] = f2bf(v2 - bf2f(h2));
        float v3 = (k < 16 && n < 8) ? W3[k * 8 + n] : 0.f;
        unsigned short h3 = f2bf(v3);
        w3fh[e] = h3; w3fl[e] = f2bf(v3 - bf2f(h3));
    }
    if (tid < 32) {
        float a = b1[tid];
        for (int c2 = 0; c2 < 256; ++c2) a += lnb[c2] * W1[c2 * 32 + tid];
        bD1[tid] = a;
        float sc = bng[tid] * rsqrtf(bnv[tid] + LN_EPS);
        bnSs[tid] = sc; bnBs[tid] = bnb[tid] - bnm[tid] * sc;
    } else if (tid < 48) b2s[tid - 32] = b2[tid - 32];
    else if (tid < 56) b3s[tid - 48] = b3[tid - 48];
    __syncthreads();

    const int wv = tid >> 6, l = tid & 63;
    const int r = l & 15, q = l >> 4;
    const int ntiles = (BB * TT) / 16;
    for (int tile = blockIdx.x * 4 + wv; tile < ntiles; tile += gridDim.x * 4) {
        const size_t rowbase = (size_t)tile * 16;
        const float* xrow = X + (rowbase + r) * FF + q * 8;
        float xd[64];
        #pragma unroll
        for (int ks = 0; ks < 8; ++ks) {
            float4 p0 = *(const float4*)(xrow + ks * 32);
            float4 p1 = *(const float4*)(xrow + ks * 32 + 4);
            xd[ks * 8 + 0] = p0.x; xd[ks * 8 + 1] = p0.y; xd[ks * 8 + 2] = p0.z; xd[ks * 8 + 3] = p0.w;
            xd[ks * 8 + 4] = p1.x; xd[ks * 8 + 5] = p1.y; xd[ks * 8 + 6] = p1.z; xd[ks * 8 + 7] = p1.w;
        }
        float s = 0.f, ss = 0.f;
        #pragma unroll
        for (int i = 0; i < 64; ++i) { s += xd[i]; ss += xd[i] * xd[i]; }
        s += __shfl_xor(s, 16);  s += __shfl_xor(s, 32);
        ss += __shfl_xor(ss, 16); ss += __shfl_xor(ss, 32);
        float mu = s * (1.0f / FF);
        float var = ss * (1.0f / FF) - mu * mu;
        float rs = rsqrtf(var + LN_EPS);

        f32x4 acc0 = {bD1[r], bD1[r], bD1[r], bD1[r]};
        f32x4 acc1 = {bD1[16 + r], bD1[16 + r], bD1[16 + r], bD1[16 + r]};
        #pragma unroll
        for (int ks = 0; ks < 8; ++ks) {
            short8 ah, al;
            #pragma unroll
            for (int j = 0; j < 8; ++j) {
                float xn = (xd[ks * 8 + j] - mu) * rs;
                unsigned short hi = f2bf(xn);
                ah[j] = (short)hi; al[j] = (short)f2bf(xn - bf2f(hi));
            }
            short8 bh0 = *(const short8*)&w1fh[((ks * 2 + 0) * 64 + l) * 8];
            short8 bl0 = *(const short8*)&w1fl[((ks * 2 + 0) * 64 + l) * 8];
            short8 bh1 = *(const short8*)&w1fh[((ks * 2 + 1) * 64 + l) * 8];
            short8 bl1 = *(const short8*)&w1fl[((ks * 2 + 1) * 64 + l) * 8];
            acc0 = __builtin_amdgcn_mfma_f32_16x16x32_bf16(ah, bh0, acc0, 0, 0, 0);
            acc0 = __builtin_amdgcn_mfma_f32_16x16x32_bf16(al, bh0, acc0, 0, 0, 0);
            acc0 = __builtin_amdgcn_mfma_f32_16x16x32_bf16(ah, bl0, acc0, 0, 0, 0);
            acc1 = __builtin_amdgcn_mfma_f32_16x16x32_bf16(ah, bh1, acc1, 0, 0, 0);
            acc1 = __builtin_amdgcn_mfma_f32_16x16x32_bf16(al, bh1, acc1, 0, 0, 0);
            acc1 = __builtin_amdgcn_mfma_f32_16x16x32_bf16(ah, bl1, acc1, 0, 0, 0);
        }
        #pragma unroll
        for (int i = 0; i < 4; ++i) {
            int row = q * 4 + i;
            float z0 = fmaxf(acc0[i], 0.f) * bnSs[r] + bnBs[r];
            float z1 = fmaxf(acc1[i], 0.f) * bnSs[16 + r] + bnBs[16 + r];
            e1s[wv][row][r] = z0;
            e1s[wv][row][16 + r] = z1;
        }
        __builtin_amdgcn_wave_barrier();

        short8 a2h, a2l;
        #pragma unroll
        for (int j = 0; j < 8; ++j) {
            float v = e1s[wv][r][q * 8 + j];
            unsigned short hi = f2bf(v);
            a2h[j] = (short)hi; a2l[j] = (short)f2bf(v - bf2f(hi));
        }
        f32x4 acc2 = {b2s[r], b2s[r], b2s[r], b2s[r]};
        {
            short8 bh = *(const short8*)&w2fh[l * 8];
            short8 bl = *(const short8*)&w2fl[l * 8];
            acc2 = __builtin_amdgcn_mfma_f32_16x16x32_bf16(a2h, bh, acc2, 0, 0, 0);
            acc2 = __builtin_amdgcn_mfma_f32_16x16x32_bf16(a2l, bh, acc2, 0, 0, 0);
            acc2 = __builtin_amdgcn_mfma_f32_16x16x32_bf16(a2h, bl, acc2, 0, 0, 0);
        }
        #pragma unroll
        for (int i = 0; i < 4; ++i) e2s[wv][q * 4 + i][r] = fmaxf(acc2[i], 0.f);
        __builtin_amdgcn_wave_barrier();

        short8 a3h = (short8){0,0,0,0,0,0,0,0}, a3l = (short8){0,0,0,0,0,0,0,0};
        if (q < 2) {
            #pragma unroll
            for (int j = 0; j < 8; ++j) {
                float v = e2s[wv][r][q * 8 + j];
                unsigned short hi = f2bf(v);
                a3h[j] = (short)hi; a3l[j] = (short)f2bf(v - bf2f(hi));
            }
        }
        float b3v = (r < 8) ? b3s[r] : 0.f;
        f32x4 acc3 = {b3v, b3v, b3v, b3v};
        {
            short8 bh = *(const short8*)&w3fh[l * 8];
            short8 bl = *(const short8*)&w3fl[l * 8];
            acc3 = __builtin_amdgcn_mfma_f32_16x16x32_bf16(a3h, bh, acc3, 0, 0, 0);
            acc3 = __builtin_amdgcn_mfma_f32_16x16x32_bf16(a3l, bh, acc3, 0, 0, 0);
            acc3 = __builtin_amdgcn_mfma_f32_16x16x32_bf16(a3h, bl, acc3, 0, 0, 0);
        }
        // hi-only frag-ready store: even r packs (hi_{r+1}<<16)|hi_r at dword r/2
        if (r < 8) {
            #pragma unroll
            for (int i = 0; i < 4; ++i) {
                size_t grow = rowbase + q * 4 + i;
                float e3 = fmaxf(acc3[i], 0.f);
                unsigned int wself = (unsigned)f2bf(e3);
                unsigned int wnbr = __shfl_xor(wself, 1);
                if ((r & 1) == 0) sqpk[grow * 4 + (r >> 1)] = (wnbr << 16) | wself;
            }
        } else if (r == 8) {
            #pragma unroll
            for (int i = 0; i < 4; ++i) {
                size_t grow = rowbase + q * 4 + i;
                yv[grow] = f2bf((float)Yp[grow]);
            }
        }
        __builtin_amdgcn_wave_barrier();
    }
}

// ===== Kernel 2a: SINGLE-pass BiLSTM, batch 16, pure bf16-hi (12 MFMA/step), r11 structure =====
// Store path trimmed: per-lane ds_write_b16 / global u16 store (no shfl/pack on critical path).
#define R1_SEQ 0u         // u32 [TT][17][4] (pad row) = 34816
#define R1_YV  34816u     // u16 [TT][16]              = 4096
#define R1_HP  38912u     // u16 [2][2][16][72]        = 9216
#define R1_SZ  48128u

__global__ __launch_bounds__(512, 1) void k_rnn1(
    const unsigned int* __restrict__ g_sqpk, const unsigned short* __restrict__ g_yv,
    const float* __restrict__ fk, const float* __restrict__ fr, const float* __restrict__ fb,
    const float* __restrict__ bk, const float* __restrict__ br, const float* __restrict__ bbv,
    unsigned short* __restrict__ enc,                     // chunk-local [csmp][T][128] u16
    float* __restrict__ hfin, float* __restrict__ cfin,   // absolute [B][128]
    int s0)
{
    __shared__ __align__(16) unsigned char arena[R1_SZ];
    unsigned int*   seqU   = (unsigned int*)(arena + R1_SEQ);
    unsigned short* yvS    = (unsigned short*)(arena + R1_YV);
    unsigned int*   hpackU = (unsigned int*)(arena + R1_HP);   // read view (dwords)
    unsigned short* hpackH = (unsigned short*)(arena + R1_HP); // write view (u16)

    const int tid = threadIdx.x;
    const int sbase = s0 + blockIdx.x * 16;
    const int wv = tid >> 6, l = tid & 63;
    const int d = wv >> 2, w = wv & 3;
    const int r = l & 15, q = l >> 4;
    const int u = (w << 4) + r;

    // stage hi-only seq: seqU[t*68 + smp*4 + j]
    for (int i = tid; i < 16 * TT * 4; i += 512) {
        int smp = i >> 9, rem = i & 511;
        int t = rem >> 2, j = rem & 3;
        seqU[t * 68 + smp * 4 + j] = g_sqpk[(size_t)(sbase + smp) * (TT * 4) + rem];
    }
    for (int i = tid; i < 16 * TT; i += 512) {
        int smp = i >> 7, t = i & 127;
        yvS[t * 16 + smp] = g_yv[(size_t)(sbase + smp) * TT + t];
    }

    const float* Wr = d ? br : fr;
    const float* Wk = d ? bk : fk;
    const float* Bz = d ? bbv : fb;
    short8 Bh[3][4];
    float bz[4];
    #pragma unroll
    for (int g = 0; g < 4; ++g) {
        int col = (g << 6) + u;
        bz[g] = Bz[col];
        #pragma unroll
        for (int kt = 0; kt < 3; ++kt) {
            #pragma unroll
            for (int j = 0; j < 8; ++j) {
                int kg = kt * 32 + q * 8 + j;
                float v = (kg < 64) ? Wr[kg * 256 + col]
                        : (kg < 73) ? Wk[(kg - 64) * 256 + col] : 0.f;
                Bh[kt][g][j] = (short)f2bf(v);
            }
        }
    }

    const unsigned int* hrd0 = hpackU + (d * 16 + r) * 36 + q * 4;
    const unsigned int* hrd1 = hrd0 + 1152;                      // + 2*16*36 dwords
    // per-lane u16 write offset within a sample row (72 u16 per row): unit u
    const int elb16 = ((blockIdx.x * 16 + q * 4) * TT) * 128 + d * 64 + u;

    for (int i = tid; i < 2304; i += 512) hpackU[i] = 0u;
    float c4[4] = {0.f, 0.f, 0.f, 0.f};
    __syncthreads();

    auto ldA2 = [&](int ts_) -> short8 {
        short8 v = (short8){0,0,0,0,0,0,0,0};
        if (q == 0)      v = *(const short8*)(seqU + ts_ * 68 + r * 4);
        else if (q == 1) v[0] = (short)yvS[ts_ * 16 + r];
        return v;
    };
    short8 A2h = ldA2(d ? (TT - 1) : 0);

    for (int t = 0; t < TT; ++t) {
        const int ts = d ? (TT - 1 - t) : t;
        const int buf = t & 1;
        const unsigned int* hp = buf ? hrd1 : hrd0;
        short8 A0h = *(const short8*)(hp);
        short8 A1h = *(const short8*)(hp + 16);
        short8 A2c = A2h;

        f32x4 z[4];
        #pragma unroll
        for (int g = 0; g < 4; ++g) {
            f32x4 acc = {bz[g], bz[g], bz[g], bz[g]};
            acc = __builtin_amdgcn_mfma_f32_16x16x32_bf16(A0h, Bh[0][g], acc, 0, 0, 0);
            acc = __builtin_amdgcn_mfma_f32_16x16x32_bf16(A1h, Bh[1][g], acc, 0, 0, 0);
            acc = __builtin_amdgcn_mfma_f32_16x16x32_bf16(A2c, Bh[2][g], acc, 0, 0, 0);
            z[g] = acc;
        }

        // prefetch next step's seq/y fragment (independent of h)
        if (t < TT - 1) A2h = ldA2(d ? (TT - 2 - t) : (t + 1));

        const int nbase = ((buf ^ 1) * 2 + d) * 16;
        #pragma unroll
        for (int i = 0; i < 4; ++i) {
            float zi = z[0][i], zf = z[1][i], zg = z[2][i], zo = z[3][i];
            float cc = sigm(zf) * c4[i] + sigm(zi) * tanhfast(zg);
            float hh = sigm(zo) * tanhfast(cc);
            c4[i] = cc;
            int smp = (q << 2) + i;
            unsigned short hb = f2bf(hh);
            hpackH[(nbase + smp) * 72 + u] = hb;                 // per-lane b16, no shfl
            enc[elb16 + i * (TT * 128) + ts * 128] = hb;         // per-lane u16, fire-and-forget
            if (t == TT - 1) {
                hfin[(size_t)(sbase + smp) * 128 + (d << 6) + u] = hh;
                cfin[(size_t)(sbase + smp) * 128 + (d << 6) + u] = cc;
            }
        }
        // LDS-only barrier: ds ops drained (lgkmcnt), global stores left in flight.
        asm volatile("s_waitcnt lgkmcnt(0)\n\ts_barrier" ::: "memory");
    }
}

// ------- Kernel 2b: per-sample attention + decoder + output softmax (proven) -------
__global__ __launch_bounds__(256, 4) void k_att(
    const unsigned short* __restrict__ enc,
    const float* __restrict__ hfin, const float* __restrict__ cfin,
    const float* __restrict__ Wsh, const float* __restrict__ bsh,
    const float* __restrict__ Wsc, const float* __restrict__ bsc,
    const float* __restrict__ Wq,  const float* __restrict__ bq,
    const float* __restrict__ dk,  const float* __restrict__ dr, const float* __restrict__ dbv,
    const float* __restrict__ Wo,  const float* __restrict__ bo,
    float* __restrict__ out, int s0)
{
    __shared__ unsigned short el[TT][136];
    __shared__ float st[128], ct[128], shS[64], scS[64], qS[128], pS[128], attS[128], zdS[256], hdS[64], red[8];

    int tid = threadIdx.x;
    int bloc = blockIdx.x;
    int s = s0 + bloc;

    for (int i = tid; i < TT * 16; i += 256) {
        int t = i >> 4, c = i & 15;
        *(short8*)&el[t][c * 8] = *(const short8*)&enc[(size_t)bloc * TT * 128 + t * 128 + c * 8];
    }
    if (tid < 128) { st[tid] = hfin[(size_t)s * 128 + tid]; ct[tid] = cfin[(size_t)s * 128 + tid]; }
    __syncthreads();

    if (tid < 128) {
        int uu = tid & 63;
        const float* Wm = (tid < 64) ? Wsh : Wsc;
        const float* sv = (tid < 64) ? st : ct;
        float a = (tid < 64) ? bsh[uu] : bsc[uu];
        #pragma unroll 4
        for (int j = 0; j < 128; ++j) a += sv[j] * Wm[j * 64 + uu];
        if (tid < 64) shS[uu] = a; else scS[uu] = a;
    }
    __syncthreads();
    if (tid < 128) {
        float a = bq[tid];
        #pragma unroll 4
        for (int uu = 0; uu < 64; ++uu) a += shS[uu] * Wq[uu * 128 + tid];
        qS[tid] = a;
    }
    __syncthreads();
    float sc_val = 0.f;
    int wvv = tid >> 6, lnn = tid & 63;
    if (tid < 128) {
        float a = 0.f;
        #pragma unroll 2
        for (int c = 0; c < 16; ++c) {
            short8 e8 = *(const short8*)&el[tid][c * 8];
            #pragma unroll
            for (int j2 = 0; j2 < 8; ++j2) a += qS[c * 8 + j2] * bf2f((unsigned short)e8[j2]);
        }
        sc_val = a;
        float m = a;
        #pragma unroll
        for (int mk = 1; mk < 64; mk <<= 1) m = fmaxf(m, __shfl_xor(m, mk));
        if (lnn == 0) red[wvv] = m;
    }
    __syncthreads();
    float gmax = fmaxf(red[0], red[1]);
    if (tid < 128) {
        float ev = expf(sc_val - gmax);
        pS[tid] = ev;
        float s2 = ev;
        #pragma unroll
        for (int mk = 1; mk < 64; mk <<= 1) s2 += __shfl_xor(s2, mk);
        if (lnn == 0) red[4 + wvv] = s2;
    }
    __syncthreads();
    float denom = red[4] + red[5];
    if (tid < 128) {
        float a = 0.f;
        #pragma unroll 4
        for (int t2 = 0; t2 < TT; ++t2) a += pS[t2] * bf2f(el[t2][tid]);
        attS[tid] = a / denom;
    }
    __syncthreads();
    if (tid < 256) {
        float a = dbv[tid];
        #pragma unroll 4
        for (int j = 0; j < 128; ++j) a += attS[j] * dk[j * 256 + tid];
        #pragma unroll 4
        for (int j = 0; j < 64; ++j)  a += shS[j] * dr[j * 256 + tid];
        zdS[tid] = a;
    }
    __syncthreads();
    if (tid < 64) {
        float zi = zdS[tid], zf = zdS[64 + tid], zg = zdS[128 + tid], zo = zdS[192 + tid];
        float cc = sigm(zf) * scS[tid] + sigm(zi) * tanhfast(zg);
        hdS[tid] = sigm(zo) * tanhfast(cc);
    }
    __syncthreads();
    if (tid < 32) {
        float a = bo[tid];
        #pragma unroll
        for (int uu = 0; uu < 64; ++uu) a += hdS[uu] * Wo[uu * 32 + tid];
        float m = a;
        #pragma unroll
        for (int mk = 1; mk < 32; mk <<= 1) m = fmaxf(m, __shfl_xor(m, mk));
        float e = expf(a - m);
        float s2 = e;
        #pragma unroll
        for (int mk = 1; mk < 32; mk <<= 1) s2 += __shfl_xor(s2, mk);
        out[(size_t)s * VV + tid] = e / s2;
    }
}

// ====== Kernel 2-fallback: fused 3-pass (r6-proven, hi-only seq; used only for tiny ws) ======
#define A_SEQ   0u
#define A_YV    34816u
#define A_HP    38912u
#define A_SGRID 56320u
#define A_SH    72704u
#define A_SC    76800u
#define A_Q     80896u
#define A_ATT   89088u
#define A_L     97280u
#define A_SZ    97344u

__global__ __launch_bounds__(512, 1) void k_rnn(
    const unsigned int* __restrict__ g_sqpk, const unsigned short* __restrict__ g_yv,
    const float* __restrict__ fk, const float* __restrict__ fr, const float* __restrict__ fb,
    const float* __restrict__ bk, const float* __restrict__ br, const float* __restrict__ bbv,
    const float* __restrict__ Wsh, const float* __restrict__ bsh,
    const float* __restrict__ Wsc, const float* __restrict__ bsc,
    const float* __restrict__ Wq,  const float* __restrict__ bq,
    const float* __restrict__ dk,  const float* __restrict__ dr, const float* __restrict__ db,
    const float* __restrict__ Wo,  const float* __restrict__ bo,
    float* __restrict__ out)
{
    __shared__ __align__(16) unsigned char arena[A_SZ];
    unsigned int*   seqU   = (unsigned int*)(arena + A_SEQ);
    unsigned short* yvS    = (unsigned short*)(arena + A_YV);
    unsigned int*   hpackU = (unsigned int*)(arena + A_HP);
    float* sgridF = (float*)(arena + A_SGRID);
    float* hfinL  = (float*)(arena + A_SGRID);
    float* cfinL  = hfinL + 2048;
    float* zdS    = (float*)(arena + A_SGRID);
    float* shS    = (float*)(arena + A_SH);
    float* scS    = (float*)(arena + A_SC);
    float* qS     = (float*)(arena + A_Q);
    float* pT     = (float*)(arena + A_Q);
    float* attS   = (float*)(arena + A_ATT);
    float* hdS    = (float*)(arena + A_ATT);
    float* lS     = (float*)(arena + A_L);

    const int tid = threadIdx.x;
    const int sbase = blockIdx.x * 16;
    const int wv = tid >> 6, l = tid & 63;
    const int d = wv >> 2, w = wv & 3;
    const int r = l & 15, q = l >> 4;
    const int u = (w << 4) + r;

    for (int i = tid; i < 16 * TT * 4; i += 512) {
        int smp = i >> 9, rem = i & 511;
        int t = rem >> 2, j = rem & 3;
        seqU[t * 68 + smp * 4 + j] = g_sqpk[(size_t)(sbase + smp) * (TT * 4) + rem];
    }
    for (int i = tid; i < 16 * TT; i += 512) {
        int smp = i >> 7, t = i & 127;
        yvS[t * 16 + smp] = g_yv[(size_t)(sbase + smp) * TT + t];
    }

    const float* Wr = d ? br : fr;
    const float* Wk = d ? bk : fk;
    const float* Bz = d ? bbv : fb;
    short8 Bh[3][4], Bl[3][4];
    float bz[4];
    #pragma unroll
    for (int g = 0; g < 4; ++g) {
        int col = (g << 6) + u;
        bz[g] = Bz[col];
        #pragma unroll
        for (int kt = 0; kt < 3; ++kt) {
            #pragma unroll
            for (int j = 0; j < 8; ++j) {
                int kg = kt * 32 + q * 8 + j;
                float v = (kg < 64) ? Wr[kg * 256 + col]
                        : (kg < 73) ? Wk[(kg - 64) * 256 + col] : 0.f;
                unsigned short hi = f2bf(v);
                Bh[kt][g][j] = (short)hi;
                Bl[kt][g][j] = (short)f2bf(v - bf2f(hi));
            }
        }
    }
    short8 Bq0h = (short8){0,0,0,0,0,0,0,0}, Bq1h = (short8){0,0,0,0,0,0,0,0};

    const unsigned int* hrd0 = hpackU + (d * 16 + r) * 68 + q * 4;
    const unsigned int* hrd1 = hrd0 + 2176;
    const int wofs = w * 8 + (r >> 1) + ((r & 1) ? 32 : 0);
    __syncthreads();

    auto run_phase = [&](auto mode_c) {
        constexpr int mode = decltype(mode_c)::value;
        for (int i = tid; i < 4352; i += 512) hpackU[i] = 0u;
        float c4[4] = {0.f, 0.f, 0.f, 0.f};
        float aacc[4] = {0.f, 0.f, 0.f, 0.f};
        __syncthreads();
        for (int t = 0; t < TT; ++t) {
            const int ts = d ? (TT - 1 - t) : t;
            const int buf = t & 1;
            const unsigned int* hp = buf ? hrd1 : hrd0;
            short8 A0h = *(const short8*)(hp);
            short8 A1h = *(const short8*)(hp + 16);
            short8 A0l = *(const short8*)(hp + 32);
            short8 A1l = *(const short8*)(hp + 48);
            short8 A2h = (short8){0,0,0,0,0,0,0,0};
            if (q == 0) {
                A2h = *(const short8*)(seqU + ts * 68 + r * 4);
            } else if (q == 1) {
                A2h[0] = (short)yvS[ts * 16 + r];
            }
            if constexpr (mode == 1) {
                if (w == 0 && t > 0) {
                    f32x4 sa = {0.f, 0.f, 0.f, 0.f};
                    sa = __builtin_amdgcn_mfma_f32_16x16x32_bf16(A0h, Bq0h, sa, 0, 0, 0);
                    sa = __builtin_amdgcn_mfma_f32_16x16x32_bf16(A1h, Bq1h, sa, 0, 0, 0);
                    if (q == (r >> 2)) {
                        int tp = d ? (TT - t) : (t - 1);
                        sgridF[(d * 16 + r) * 128 + tp] = sa[r & 3];
                    }
                }
            }
            f32x4 z[4];
            #pragma unroll
            for (int g = 0; g < 4; ++g) {
                f32x4 acc = {bz[g], bz[g], bz[g], bz[g]};
                acc = __builtin_amdgcn_mfma_f32_16x16x32_bf16(A0h, Bh[0][g], acc, 0, 0, 0);
                acc = __builtin_amdgcn_mfma_f32_16x16x32_bf16(A0l, Bh[0][g], acc, 0, 0, 0);
                acc = __builtin_amdgcn_mfma_f32_16x16x32_bf16(A0h, Bl[0][g], acc, 0, 0, 0);
                acc = __builtin_amdgcn_mfma_f32_16x16x32_bf16(A1h, Bh[1][g], acc, 0, 0, 0);
                acc = __builtin_amdgcn_mfma_f32_16x16x32_bf16(A1l, Bh[1][g], acc, 0, 0, 0);
                acc = __builtin_amdgcn_mfma_f32_16x16x32_bf16(A1h, Bl[1][g], acc, 0, 0, 0);
                acc = __builtin_amdgcn_mfma_f32_16x16x32_bf16(A2h, Bh[2][g], acc, 0, 0, 0);
                acc = __builtin_amdgcn_mfma_f32_16x16x32_bf16(A2h, Bl[2][g], acc, 0, 0, 0);
                z[g] = acc;
            }
            const int nbase = ((buf ^ 1) * 2 + d) * 16;
            #pragma unroll
            for (int i = 0; i < 4; ++i) {
                float zi = z[0][i], zf = z[1][i], zg = z[2][i], zo = z[3][i];
                float cc = sigm(zf) * c4[i] + sigm(zi) * tanhfast(zg);
                float hh = sigm(zo) * tanhfast(cc);
                c4[i] = cc;
                int smp = (q << 2) + i;
                unsigned short bfh = f2bf(hh);
                unsigned short bfe = f2bf(hh - bf2f(bfh));
                unsigned int wself = ((unsigned)bfh << 16) | (unsigned)bfe;
                unsigned int wnbr = __shfl_xor(wself, 1);
                unsigned int outw = (r & 1) ? ((wself << 16) | (wnbr & 0xFFFFu))
                                            : ((wnbr & 0xFFFF0000u) | (wself >> 16));
                hpackU[(nbase + smp) * 68 + wofs] = outw;
                if constexpr (mode == 2) aacc[i] += pT[ts * 16 + smp] * hh;
                if constexpr (mode == 0) {
                    if (t == TT - 1) {
                        hfinL[smp * 128 + (d << 6) + u] = hh;
                        cfinL[smp * 128 + (d << 6) + u] = cc;
                    }
                }
            }
            __syncthreads();
        }
        if constexpr (mode == 1) {
            if (w == 0) {
                short8 A0h = *(const short8*)(hrd0);
                short8 A1h = *(const short8*)(hrd0 + 16);
                f32x4 sa = {0.f, 0.f, 0.f, 0.f};
                sa = __builtin_amdgcn_mfma_f32_16x16x32_bf16(A0h, Bq0h, sa, 0, 0, 0);
                sa = __builtin_amdgcn_mfma_f32_16x16x32_bf16(A1h, Bq1h, sa, 0, 0, 0);
                if (q == (r >> 2)) {
                    int tp = d ? 0 : (TT - 1);
                    sgridF[(d * 16 + r) * 128 + tp] = sa[r & 3];
                }
            }
            __syncthreads();
        }
        if constexpr (mode == 2) {
            #pragma unroll
            for (int i = 0; i < 4; ++i) {
                int smp = (q << 2) + i;
                attS[smp * 128 + (d << 6) + u] = aacc[i] / lS[smp];
            }
            __syncthreads();
        }
    };

    run_phase(IC<0>{});
    for (int o = tid; o < 2048; o += 512) {
        int kind = o >> 10, smp = (o >> 6) & 15, uu = o & 63;
        const float* src = kind ? (cfinL + smp * 128) : (hfinL + smp * 128);
        const float* Wm = kind ? Wsc : Wsh;
        float a = kind ? bsc[uu] : bsh[uu];
        #pragma unroll 4
        for (int j = 0; j < 128; ++j) a += src[j] * Wm[j * 64 + uu];
        (kind ? scS : shS)[smp * 64 + uu] = a;
    }
    __syncthreads();
    for (int o = tid; o < 2048; o += 512) {
        int smp = o >> 7, dd = o & 127;
        float a = bq[dd];
        #pragma unroll 4
        for (int j = 0; j < 64; ++j) a += shS[smp * 64 + j] * Wq[j * 128 + dd];
        qS[smp * 128 + dd] = a;
    }
    __syncthreads();
    if (w == 0) {
        #pragma unroll
        for (int j = 0; j < 8; ++j) {
            Bq0h[j] = (short)f2bf(qS[r * 128 + (d << 6) + q * 8 + j]);
            Bq1h[j] = (short)f2bf(qS[r * 128 + (d << 6) + 32 + q * 8 + j]);
        }
    }
    __syncthreads();

    run_phase(IC<1>{});
    {
        int smp = tid >> 5, sl = tid & 31;
        float sv[4];
        #pragma unroll
        for (int p = 0; p < 4; ++p) {
            int t = sl + 32 * p;
            sv[p] = sgridF[smp * 128 + t] + sgridF[(16 + smp) * 128 + t];
        }
        float m = fmaxf(fmaxf(sv[0], sv[1]), fmaxf(sv[2], sv[3]));
        #pragma unroll
        for (int mk = 1; mk < 32; mk <<= 1) m = fmaxf(m, __shfl_xor(m, mk));
        float lsum = 0.f;
        #pragma unroll
        for (int p = 0; p < 4; ++p) lsum += __expf(sv[p] - m);
        #pragma unroll
        for (int mk = 1; mk < 32; mk <<= 1) lsum += __shfl_xor(lsum, mk);
        __syncthreads();
        #pragma unroll
        for (int p = 0; p < 4; ++p) pT[(sl + 32 * p) * 16 + smp] = __expf(sv[p] - m);
        if (sl == 0) lS[smp] = lsum;
    }
    __syncthreads();

    run_phase(IC<2>{});

    for (int o = tid; o < 4096; o += 512) {
        int smp = o >> 8, col = o & 255;
        float a = db[col];
        #pragma unroll 4
        for (int j = 0; j < 128; ++j) a += attS[smp * 128 + j] * dk[j * 256 + col];
        #pragma unroll 4
        for (int j = 0; j < 64; ++j)  a += shS[smp * 64 + j] * dr[j * 256 + col];
        zdS[smp * 256 + col] = a;
    }
    __syncthreads();
    for (int o = tid; o < 1024; o += 512) {
        int smp = o >> 6, uu = o & 63;
        float zi = zdS[smp * 256 + uu], zf = zdS[smp * 256 + 64 + uu];
        float zg = zdS[smp * 256 + 128 + uu], zo = zdS[smp * 256 + 192 + uu];
        float cc = sigm(zf) * scS[smp * 64 + uu] + sigm(zi) * tanhfast(zg);
        hdS[smp * 64 + uu] = sigm(zo) * tanhfast(cc);
    }
    __syncthreads();
    {
        int smp = tid >> 5, v = tid & 31;
        float a = bo[v];
        #pragma unroll 4
        for (int j = 0; j < 64; ++j) a += hdS[smp * 64 + j] * Wo[j * 32 + v];
        float m = a;
        #pragma unroll
        for (int mk = 1; mk < 32; mk <<= 1) m = fmaxf(m, __shfl_xor(m, mk));
        float e = __expf(a - m);
        float s2 = e;
        #pragma unroll
        for (int mk = 1; mk < 32; mk <<= 1) s2 += __shfl_xor(s2, mk);
        out[(size_t)(sbase + smp) * VV + v] = e / s2;
    }
}

extern "C" void kernel_launch(void* const* d_in, const int* in_sizes, int n_in,
                              void* d_out, int out_size, void* d_ws, size_t ws_size,
                              hipStream_t stream) {
    const float* X   = (const float*)d_in[0];
    const int*   Yp  = (const int*)d_in[1];
    const float* lng = (const float*)d_in[2];
    const float* lnb = (const float*)d_in[3];
    const float* W1  = (const float*)d_in[4];
    const float* b1  = (const float*)d_in[5];
    const float* bng = (const float*)d_in[6];
    const float* bnb = (const float*)d_in[7];
    const float* bnm = (const float*)d_in[8];
    const float* bnv = (const float*)d_in[9];
    const float* W2  = (const float*)d_in[10];
    const float* b2  = (const float*)d_in[11];
    const float* W3  = (const float*)d_in[12];
    const float* b3  = (const float*)d_in[13];
    const float* fk  = (const float*)d_in[14];
    const float* fr  = (const float*)d_in[15];
    const float* fb  = (const float*)d_in[16];
    const float* bk  = (const float*)d_in[17];
    const float* br  = (const float*)d_in[18];
    const float* bbv = (const float*)d_in[19];
    const float* Wsh = (const float*)d_in[20];
    const float* bsh = (const float*)d_in[21];
    const float* Wsc = (const float*)d_in[22];
    const float* bsc = (const float*)d_in[23];
    const float* Wq  = (const float*)d_in[24];
    const float* bq  = (const float*)d_in[25];
    const float* dk  = (const float*)d_in[26];
    const float* dr  = (const float*)d_in[27];
    const float* db  = (const float*)d_in[28];
    const float* Wo  = (const float*)d_in[29];
    const float* bo  = (const float*)d_in[30];

    // ws: sqpk u32[B*T*4] (8MB) | yv u16[B*T] (1MB) | hfin/cfin f32[B*128] (4MB) | enc u16[cs*T*128]
    unsigned int*   sqpk = (unsigned int*)d_ws;
    unsigned short* yv   = (unsigned short*)(sqpk + (size_t)BB * TT * 4);
    float*          hfin = (float*)(yv + (size_t)BB * TT);
    float*          cfin = hfin + (size_t)BB * 128;
    unsigned short* encp = (unsigned short*)(cfin + (size_t)BB * 128);
    const size_t baseB = (size_t)((char*)encp - (char*)d_ws);
    const size_t encFull = (size_t)BB * TT * 128 * 2;

    int nch = 0;
    if      (ws_size >= baseB + encFull)     nch = 1;
    else if (ws_size >= baseB + encFull / 2) nch = 2;
    else if (ws_size >= baseB + encFull / 4) nch = 4;
    else if (ws_size >= baseB + encFull / 8) nch = 8;

    k_mlp2<<<768, 256, 0, stream>>>(X, Yp, lng, lnb, W1, b1, bng, bnb, bnm, bnv,
                                    W2, b2, W3, b3, sqpk, yv);
    if (nch) {
        const int cs = BB / nch;
        for (int c = 0; c < nch; ++c) {
            int s0 = c * cs;
            k_rnn1<<<cs / 16, 512, 0, stream>>>(sqpk, yv, fk, fr, fb, bk, br, bbv,
                                                encp, hfin, cfin, s0);
            k_att<<<cs, 256, 0, stream>>>(encp, hfin, cfin,
                                          Wsh, bsh, Wsc, bsc, Wq, bq,
                                          dk, dr, db, Wo, bo, (float*)d_out, s0);
        }
    } else {
        k_rnn<<<BB / 16, 512, 0, stream>>>(sqpk, yv, fk, fr, fb, bk, br, bbv,
                                           Wsh, bsh, Wsc, bsc, Wq, bq, dk, dr, db, Wo, bo,
                                           (float*)d_out);
    }
}